// Round 1
// baseline (4815.695 us; speedup 1.0000x reference)
//
#include <hip/hip_runtime.h>
#include <math.h>

#define NEGINF_F (-1e38f)

// ---------------------------------------------------------------------------
// tscores[k][j] = sum_a A_from[k][a]*A_to[a][j]  (+ NEGINF on diagonal)
// ---------------------------------------------------------------------------
__global__ __launch_bounds__(128) void tsc_kernel(
    const float* __restrict__ Af, const float* __restrict__ At,
    float* __restrict__ tsc)
{
    int k = blockIdx.x, j = threadIdx.x;
    float s = 0.f;
#pragma unroll 8
    for (int a = 0; a < 64; ++a) s = fmaf(Af[k * 64 + a], At[a * 128 + j], s);
    if (j == k) s += NEGINF_F;
    tsc[k * 128 + j] = s;
}

// ---------------------------------------------------------------------------
// pi = log_softmax(uniqenc @ W_init + b_init) ; one block per batch row
// ---------------------------------------------------------------------------
__global__ __launch_bounds__(128) void pi_kernel(
    const float* __restrict__ u, const float* __restrict__ W,
    const float* __restrict__ b, float* __restrict__ pi)
{
    __shared__ float ul[1024];
    __shared__ float red[2];
    int bi = blockIdx.x, j = threadIdx.x;
    for (int i = j; i < 1024; i += 128) ul[i] = u[bi * 1024 + i];
    __syncthreads();
    float acc = b[j];
#pragma unroll 4
    for (int i = 0; i < 1024; ++i) acc = fmaf(ul[i], W[i * 128 + j], acc);
    // block max over 128 threads (2 waves)
    float m = acc;
#pragma unroll
    for (int off = 32; off >= 1; off >>= 1) m = fmaxf(m, __shfl_xor(m, off, 64));
    if ((j & 63) == 0) red[j >> 6] = m;
    __syncthreads();
    m = fmaxf(red[0], red[1]);
    float s = expf(acc - m);
#pragma unroll
    for (int off = 32; off >= 1; off >>= 1) s += __shfl_xor(s, off, 64);
    __syncthreads();
    if ((j & 63) == 0) red[j >> 6] = s;
    __syncthreads();
    float logZ = m + logf(red[0] + red[1]);
    pi[bi * 128 + j] = acc - logZ;
}

// ---------------------------------------------------------------------------
// fp32 SGEMM: C = A(MxK) @ B(KxN) + bias, optional relu.
// 128x128 block tile, BK=16, 256 threads, 8x8 micro-tile.
// ---------------------------------------------------------------------------
template <bool RELU>
__global__ __launch_bounds__(256) void sgemm128(
    const float* __restrict__ A, const float* __restrict__ B,
    const float* __restrict__ bias, float* __restrict__ C,
    int M, int N, int Kd)
{
    __shared__ float As[16][132];   // transposed A tile: As[k][m], padded
    __shared__ float Bs[16][132];   // Bs[k][n], padded
    const int tid = threadIdx.x;
    const int row0 = blockIdx.y * 128, col0 = blockIdx.x * 128;
    const int tx = tid & 15, ty = tid >> 4;
    const int ar = tid >> 2, ac4 = (tid & 3) * 4;     // A: row 0..63, k-seg
    const int bkr = tid >> 5, bc4 = (tid & 31) * 4;   // B: k-row 0..7, col-seg

    float c[8][8];
#pragma unroll
    for (int i = 0; i < 8; ++i)
#pragma unroll
        for (int jj = 0; jj < 8; ++jj) c[i][jj] = 0.f;

    for (int k0 = 0; k0 < Kd; k0 += 16) {
        __syncthreads();
        float4 a0 = *(const float4*)&A[(row0 + ar) * Kd + k0 + ac4];
        float4 a1 = *(const float4*)&A[(row0 + ar + 64) * Kd + k0 + ac4];
        float4 b0 = *(const float4*)&B[(k0 + bkr) * N + col0 + bc4];
        float4 b1 = *(const float4*)&B[(k0 + bkr + 8) * N + col0 + bc4];
        As[ac4 + 0][ar] = a0.x; As[ac4 + 1][ar] = a0.y;
        As[ac4 + 2][ar] = a0.z; As[ac4 + 3][ar] = a0.w;
        As[ac4 + 0][ar + 64] = a1.x; As[ac4 + 1][ar + 64] = a1.y;
        As[ac4 + 2][ar + 64] = a1.z; As[ac4 + 3][ar + 64] = a1.w;
        *(float4*)&Bs[bkr][bc4] = b0;
        *(float4*)&Bs[bkr + 8][bc4] = b1;
        __syncthreads();
#pragma unroll
        for (int kk = 0; kk < 16; ++kk) {
            float4 t0 = *(float4*)&As[kk][ty * 4];
            float4 t1 = *(float4*)&As[kk][64 + ty * 4];
            float4 t2 = *(float4*)&Bs[kk][tx * 4];
            float4 t3 = *(float4*)&Bs[kk][64 + tx * 4];
            float av[8] = {t0.x, t0.y, t0.z, t0.w, t1.x, t1.y, t1.z, t1.w};
            float bv[8] = {t2.x, t2.y, t2.z, t2.w, t3.x, t3.y, t3.z, t3.w};
#pragma unroll
            for (int i = 0; i < 8; ++i)
#pragma unroll
                for (int jj = 0; jj < 8; ++jj)
                    c[i][jj] = fmaf(av[i], bv[jj], c[i][jj]);
        }
    }
#pragma unroll
    for (int i = 0; i < 8; ++i) {
        int mrow = row0 + ((i < 4) ? (ty * 4 + i) : (64 + ty * 4 + i - 4));
        float* Crow = C + mrow * N + col0;
#pragma unroll
        for (int jb = 0; jb < 2; ++jb) {
            int cc = jb * 64 + tx * 4;
            float4 bv = *(const float4*)&bias[col0 + cc];
            float4 v;
            v.x = c[i][jb * 4 + 0] + bv.x;
            v.y = c[i][jb * 4 + 1] + bv.y;
            v.z = c[i][jb * 4 + 2] + bv.z;
            v.w = c[i][jb * 4 + 3] + bv.w;
            if (RELU) {
                v.x = fmaxf(v.x, 0.f); v.y = fmaxf(v.y, 0.f);
                v.z = fmaxf(v.z, 0.f); v.w = fmaxf(v.w, 0.f);
            }
            *(float4*)&Crow[cc] = v;
        }
    }
}

// ---------------------------------------------------------------------------
// trans: per batch b, S[k][j] = tsc[k][j] + dot64(cond_from[b,k], cond_to[b,j]);
// P[b,k,j] = softmax_j(S)[k][j]  (probability form; log_softmax then exp)
// ---------------------------------------------------------------------------
__global__ __launch_bounds__(256) void trans_kernel(
    const float* __restrict__ cond, const float* __restrict__ tsc,
    float* __restrict__ P)
{
    __shared__ float cf[128 * 68];  // cond_from rows padded to 68
    __shared__ float ct[128 * 68];  // cond_to rows padded to 68
    int b = blockIdx.x, tid = threadIdx.x;
    const float* cb = cond + b * 16384;
    for (int u = tid; u < 2048; u += 256) {
        int k = u >> 4, a4 = (u & 15) * 4;
        *(float4*)&cf[k * 68 + a4] = *(const float4*)&cb[k * 128 + a4];
        *(float4*)&ct[k * 68 + a4] = *(const float4*)&cb[k * 128 + 64 + a4];
    }
    __syncthreads();
    int w = tid >> 6, lane = tid & 63;
    for (int k = w; k < 128; k += 4) {
        float s0 = tsc[k * 128 + lane];
        float s1 = tsc[k * 128 + 64 + lane];
#pragma unroll
        for (int a4 = 0; a4 < 64; a4 += 4) {
            float4 c4 = *(float4*)&cf[k * 68 + a4];
            float4 t0 = *(float4*)&ct[lane * 68 + a4];
            float4 t1 = *(float4*)&ct[(lane + 64) * 68 + a4];
            s0 = fmaf(c4.x, t0.x, fmaf(c4.y, t0.y, fmaf(c4.z, t0.z, fmaf(c4.w, t0.w, s0))));
            s1 = fmaf(c4.x, t1.x, fmaf(c4.y, t1.y, fmaf(c4.z, t1.z, fmaf(c4.w, t1.w, s1))));
        }
        float m = fmaxf(s0, s1);
#pragma unroll
        for (int off = 32; off >= 1; off >>= 1) m = fmaxf(m, __shfl_xor(m, off, 64));
        float es = expf(s0 - m) + expf(s1 - m);
#pragma unroll
        for (int off = 32; off >= 1; off >>= 1) es += __shfl_xor(es, off, 64);
        float logZ = m + logf(es);
        P[(b * 128 + k) * 128 + lane] = expf(s0 - logZ);
        P[(b * 128 + k) * 128 + 64 + lane] = expf(s1 - logZ);
    }
}

// ---------------------------------------------------------------------------
// scan: one block per batch. P[b] (64KB) staged in LDS. buf ring in registers
// (thread k owns column k). 60 steps:
//   alpha[k] = LSE_l(buf[l][k] + obs[l, t-l, b, k] + len_lp)
//   m = max_k alpha; e = exp(alpha-m); s[j] = sum_k e[k]*P[k][j]
//   astar[j] = m + log(s[j]); shift buf.  out[b] = LSE_k(alpha_59)
// ---------------------------------------------------------------------------
__global__ __launch_bounds__(256) void scan_kernel(
    const float* __restrict__ obs, const float* __restrict__ pi,
    const float* __restrict__ P, float* __restrict__ out)
{
    __shared__ float Pl[128 * 128];
    __shared__ float part[2][128];
    __shared__ float e_lds[128];
    __shared__ float redm[2];
    __shared__ float reds[2];
    const float LENLP = -1.791759469228055f;  // -log(6)
    int b = blockIdx.x, tid = threadIdx.x;
    for (int u = tid; u < 4096; u += 256)
        *(float4*)&Pl[u * 4] = *(const float4*)&P[b * 16384 + u * 4];

    float bufr[6];
    if (tid < 128) {
        bufr[0] = pi[b * 128 + tid];
#pragma unroll
        for (int l = 1; l < 6; ++l) bufr[l] = NEGINF_F;
    }
    __syncthreads();

    const int j = tid & 127, half = tid >> 7, k0 = half * 64;

    for (int t = 0; t < 60; ++t) {
        float alpha = NEGINF_F, ev = 0.f;
        if (tid < 128) {
            float vals[6];
            float am = -3.0e38f;
#pragma unroll
            for (int l = 0; l < 6; ++l) {
                int tt = t - l;
                float v = -3.0e38f;
                if (tt >= 0)
                    v = bufr[l] + obs[((l * 60 + tt) * 1024 + b) * 128 + tid] + LENLP;
                vals[l] = v;
                am = fmaxf(am, v);
            }
            float ss = 0.f;
#pragma unroll
            for (int l = 0; l < 6; ++l) ss += expf(vals[l] - am);
            alpha = am + logf(ss);
            float mm = alpha;
#pragma unroll
            for (int off = 32; off >= 1; off >>= 1) mm = fmaxf(mm, __shfl_xor(mm, off, 64));
            if ((tid & 63) == 0) redm[tid >> 6] = mm;
        }
        __syncthreads();                       // [A]
        float m = fmaxf(redm[0], redm[1]);
        if (tid < 128) {
            ev = expf(alpha - m);
            e_lds[tid] = ev;
        }
        __syncthreads();                       // [B]
        float acc = 0.f;
#pragma unroll 8
        for (int kk = 0; kk < 64; ++kk)
            acc = fmaf(e_lds[k0 + kk], Pl[(k0 + kk) * 128 + j], acc);
        part[half][j] = acc;
        __syncthreads();                       // [C]
        if (tid < 128) {
            float s = part[0][tid] + part[1][tid];
            float astar = m + logf(s);         // s==0 -> -inf, propagates safely
#pragma unroll
            for (int l = 5; l >= 1; --l) bufr[l] = bufr[l - 1];
            bufr[0] = astar;
        }
        if (t == 59) {
            float sv = (tid < 128) ? ev : 0.f;
#pragma unroll
            for (int off = 32; off >= 1; off >>= 1) sv += __shfl_xor(sv, off, 64);
            if (tid < 128 && (tid & 63) == 0) reds[tid >> 6] = sv;
            __syncthreads();                   // [D] uniform (t is uniform)
            if (tid == 0) out[b] = m + logf(reds[0] + reds[1]);
        }
    }
}

// ---------------------------------------------------------------------------
extern "C" void kernel_launch(void* const* d_in, const int* in_sizes, int n_in,
                              void* d_out, int out_size, void* d_ws, size_t ws_size,
                              hipStream_t stream)
{
    const float* uniqenc = (const float*)d_in[0];
    const float* obs_lps = (const float*)d_in[1];
    const float* W_init  = (const float*)d_in[2];
    const float* b_init  = (const float*)d_in[3];
    const float* A_from  = (const float*)d_in[4];
    const float* A_to    = (const float*)d_in[5];
    const float* W_c1    = (const float*)d_in[6];
    const float* b_c1    = (const float*)d_in[7];
    const float* W_c2    = (const float*)d_in[8];
    const float* b_c2    = (const float*)d_in[9];
    float* out = (float*)d_out;

    float* ws   = (float*)d_ws;
    float* pi   = ws;                    // 1024*128
    float* h    = pi + 131072;           // 1024*8192
    float* cond = h + 8388608;           // 1024*16384
    float* tsc  = cond + 16777216;       // 128*128
    float* P    = tsc + 16384;           // 1024*128*128

    tsc_kernel<<<128, 128, 0, stream>>>(A_from, A_to, tsc);
    pi_kernel<<<1024, 128, 0, stream>>>(uniqenc, W_init, b_init, pi);
    sgemm128<true><<<dim3(64, 8), 256, 0, stream>>>(uniqenc, W_c1, b_c1, h,
                                                    1024, 8192, 1024);
    sgemm128<false><<<dim3(128, 8), 256, 0, stream>>>(h, W_c2, b_c2, cond,
                                                      1024, 16384, 8192);
    trans_kernel<<<1024, 256, 0, stream>>>(cond, tsc, P);
    scan_kernel<<<1024, 256, 0, stream>>>(obs_lps, pi, P, out);
}

// Round 2
// 1991.686 us; speedup vs baseline: 2.4179x; 2.4179x over previous
//
#include <hip/hip_runtime.h>
#include <math.h>

#define NEGINF_F (-1e38f)

typedef _Float16 half8 __attribute__((ext_vector_type(8)));
typedef float floatx4 __attribute__((ext_vector_type(4)));

__device__ __forceinline__ void async_lds16(const void* g, void* l) {
    __builtin_amdgcn_global_load_lds(
        (const __attribute__((address_space(1))) void*)g,
        (__attribute__((address_space(3))) void*)l, 16, 0, 0);
}

// ---------------------------------------------------------------------------
// tscores[k][j] = sum_a A_from[k][a]*A_to[a][j]  (+ NEGINF on diagonal)
// ---------------------------------------------------------------------------
__global__ __launch_bounds__(128) void tsc_kernel(
    const float* __restrict__ Af, const float* __restrict__ At,
    float* __restrict__ tsc)
{
    int k = blockIdx.x, j = threadIdx.x;
    float s = 0.f;
#pragma unroll 8
    for (int a = 0; a < 64; ++a) s = fmaf(Af[k * 64 + a], At[a * 128 + j], s);
    if (j == k) s += NEGINF_F;
    tsc[k * 128 + j] = s;
}

// ---------------------------------------------------------------------------
// pi = log_softmax(uniqenc @ W_init + b_init) ; one block per batch row
// ---------------------------------------------------------------------------
__global__ __launch_bounds__(128) void pi_kernel(
    const float* __restrict__ u, const float* __restrict__ W,
    const float* __restrict__ b, float* __restrict__ pi)
{
    __shared__ float ul[1024];
    __shared__ float red[2];
    int bi = blockIdx.x, j = threadIdx.x;
    for (int i = j; i < 1024; i += 128) ul[i] = u[bi * 1024 + i];
    __syncthreads();
    float acc = b[j];
#pragma unroll 4
    for (int i = 0; i < 1024; ++i) acc = fmaf(ul[i], W[i * 128 + j], acc);
    float m = acc;
#pragma unroll
    for (int off = 32; off >= 1; off >>= 1) m = fmaxf(m, __shfl_xor(m, off, 64));
    if ((j & 63) == 0) red[j >> 6] = m;
    __syncthreads();
    m = fmaxf(red[0], red[1]);
    float s = expf(acc - m);
#pragma unroll
    for (int off = 32; off >= 1; off >>= 1) s += __shfl_xor(s, off, 64);
    __syncthreads();
    if ((j & 63) == 0) red[j >> 6] = s;
    __syncthreads();
    float logZ = m + logf(red[0] + red[1]);
    pi[bi * 128 + j] = acc - logZ;
}

// ---------------------------------------------------------------------------
// fp32 -> fp16 elementwise (uniqenc)
// ---------------------------------------------------------------------------
__global__ __launch_bounds__(256) void cvt_kernel(
    const float* __restrict__ in, _Float16* __restrict__ out)
{
    int i = (blockIdx.x * 256 + threadIdx.x) * 4;
    float4 v = *(const float4*)&in[i];
    _Float16 h[4] = {(_Float16)v.x, (_Float16)v.y, (_Float16)v.z, (_Float16)v.w};
    *(ushort4*)&out[i] = *(ushort4*)h;
}

// ---------------------------------------------------------------------------
// MFMA fp16 GEMM: C = A(MxK fp16) @ B(KxN fp32, converted in staging) + bias
// 128x128 tile, BK=32, 256 threads (4 waves, 64x64 quadrant each, 4x4 MFMA).
// A staged via global_load_lds(16B); B transposed+cvt'd through VGPRs.
// XOR swizzle (seg p = q ^ ((row>>1)&3)) keeps ds_read_b128 at 2-way.
// SPLIT_RELU=1: out = fp16 relu(acc+bias)  (GEMM2 -> h)
// SPLIT_RELU=0: out = fp32 acc+bias        (GEMM3 -> cond)
// ---------------------------------------------------------------------------
template <int SPLIT_RELU>
__global__ __launch_bounds__(256) void gemm_f16(
    const _Float16* __restrict__ A, const float* __restrict__ B,
    const float* __restrict__ bias, float* __restrict__ Cf,
    _Float16* __restrict__ Ch, int Kd, int N)
{
    __shared__ _Float16 Asm[128 * 32];
    __shared__ _Float16 Bsm[128 * 32];
    const int tid = threadIdx.x;
    const int row0 = blockIdx.x * 128, col0 = blockIdx.y * 128;

    // A staging: 2 chunks of 16B per thread, LDS offset = u*16B (lane-ordered)
    const int u0 = tid, u1 = tid + 256;
    const int ar0 = u0 >> 2, ap0 = u0 & 3;
    const int ar1 = u1 >> 2, ap1 = u1 & 3;
    const int aq0 = ap0 ^ ((ar0 >> 1) & 3);
    const int aq1 = ap1 ^ ((ar1 >> 1) & 3);
    const _Float16* Arow0 = A + (size_t)(row0 + ar0) * Kd + aq0 * 8;
    const _Float16* Arow1 = A + (size_t)(row0 + ar1) * Kd + aq1 * 8;

    // B loads: thread covers row k=tid>>3, 4 float4 chunks along n
    const int bk = tid >> 3;
    const int bn = (tid & 7) * 4;
    const float* Bptr = B + (size_t)bk * N + col0 + bn;
    const int bp_base = bk >> 3, be = bk & 7;

    const int lane = tid & 63;
    const int wm = ((tid >> 6) & 1) * 64, wn = ((tid >> 6) >> 1) * 64;
    const int lr = lane & 15, lq = lane >> 4;

    floatx4 acc[4][4];
#pragma unroll
    for (int i = 0; i < 4; ++i)
#pragma unroll
        for (int j = 0; j < 4; ++j) acc[i][j] = (floatx4)0.f;

    const int nsteps = Kd / 32;
    float4 breg[4];
#pragma unroll
    for (int c = 0; c < 4; ++c) breg[c] = *(const float4*)(Bptr + c * 32);

    for (int s = 0; s < nsteps; ++s) {
        const int k0 = s * 32;
        __syncthreads();  // LDS consumers of step s-1 done
        async_lds16(Arow0 + k0, &Asm[u0 * 8]);
        async_lds16(Arow1 + k0, &Asm[u1 * 8]);
        // B: cvt fp32->fp16, write transposed+swizzled
#pragma unroll
        for (int c = 0; c < 4; ++c) {
            float vv[4] = {breg[c].x, breg[c].y, breg[c].z, breg[c].w};
#pragma unroll
            for (int i = 0; i < 4; ++i) {
                int n = bn + c * 32 + i;
                int p = bp_base ^ ((n >> 1) & 3);
                Bsm[n * 32 + p * 8 + be] = (_Float16)vv[i];
            }
        }
        __syncthreads();  // drains A async + B lds writes
        if (s + 1 < nsteps) {
#pragma unroll
            for (int c = 0; c < 4; ++c)
                breg[c] = *(const float4*)(Bptr + (size_t)(k0 + 32) * N + c * 32);
        }
        half8 af[4], bf[4];
#pragma unroll
        for (int i = 0; i < 4; ++i) {
            int r = wm + i * 16 + lr;
            int p = lq ^ ((r >> 1) & 3);
            af[i] = *(half8*)&Asm[r * 32 + p * 8];
        }
#pragma unroll
        for (int j = 0; j < 4; ++j) {
            int r = wn + j * 16 + lr;
            int p = lq ^ ((r >> 1) & 3);
            bf[j] = *(half8*)&Bsm[r * 32 + p * 8];
        }
#pragma unroll
        for (int i = 0; i < 4; ++i)
#pragma unroll
            for (int j = 0; j < 4; ++j)
                acc[i][j] = __builtin_amdgcn_mfma_f32_16x16x32_f16(
                    af[i], bf[j], acc[i][j], 0, 0, 0);
    }

    // epilogue: C/D layout col=lane&15, row=(lane>>4)*4+reg
#pragma unroll
    for (int i = 0; i < 4; ++i) {
#pragma unroll
        for (int j = 0; j < 4; ++j) {
            int col = col0 + wn + j * 16 + lr;
            float bv = bias[col];
#pragma unroll
            for (int rr = 0; rr < 4; ++rr) {
                int row = row0 + wm + i * 16 + lq * 4 + rr;
                float v = acc[i][j][rr] + bv;
                if (SPLIT_RELU) {
                    v = fmaxf(v, 0.f);
                    Ch[(size_t)row * N + col] = (_Float16)v;
                } else {
                    Cf[(size_t)row * N + col] = v;
                }
            }
        }
    }
}

// ---------------------------------------------------------------------------
// trans: per batch b, S[k][j] = tsc[k][j] + dot64(cond_from[b,k], cond_to[b,j]);
// P[b,k,j] = softmax_j(S)[k][j]
// ---------------------------------------------------------------------------
__global__ __launch_bounds__(256) void trans_kernel(
    const float* __restrict__ cond, const float* __restrict__ tsc,
    float* __restrict__ P)
{
    __shared__ float cf[128 * 68];
    __shared__ float ct[128 * 68];
    int b = blockIdx.x, tid = threadIdx.x;
    const float* cb = cond + b * 16384;
    for (int u = tid; u < 2048; u += 256) {
        int k = u >> 4, a4 = (u & 15) * 4;
        *(float4*)&cf[k * 68 + a4] = *(const float4*)&cb[k * 128 + a4];
        *(float4*)&ct[k * 68 + a4] = *(const float4*)&cb[k * 128 + 64 + a4];
    }
    __syncthreads();
    int w = tid >> 6, lane = tid & 63;
    for (int k = w; k < 128; k += 4) {
        float s0 = tsc[k * 128 + lane];
        float s1 = tsc[k * 128 + 64 + lane];
#pragma unroll
        for (int a4 = 0; a4 < 64; a4 += 4) {
            float4 c4 = *(float4*)&cf[k * 68 + a4];
            float4 t0 = *(float4*)&ct[lane * 68 + a4];
            float4 t1 = *(float4*)&ct[(lane + 64) * 68 + a4];
            s0 = fmaf(c4.x, t0.x, fmaf(c4.y, t0.y, fmaf(c4.z, t0.z, fmaf(c4.w, t0.w, s0))));
            s1 = fmaf(c4.x, t1.x, fmaf(c4.y, t1.y, fmaf(c4.z, t1.z, fmaf(c4.w, t1.w, s1))));
        }
        float m = fmaxf(s0, s1);
#pragma unroll
        for (int off = 32; off >= 1; off >>= 1) m = fmaxf(m, __shfl_xor(m, off, 64));
        float es = expf(s0 - m) + expf(s1 - m);
#pragma unroll
        for (int off = 32; off >= 1; off >>= 1) es += __shfl_xor(es, off, 64);
        float logZ = m + logf(es);
        P[(b * 128 + k) * 128 + lane] = expf(s0 - logZ);
        P[(b * 128 + k) * 128 + 64 + lane] = expf(s1 - logZ);
    }
}

// ---------------------------------------------------------------------------
// scan: one block per batch. P[b] staged in LDS.
// ---------------------------------------------------------------------------
__global__ __launch_bounds__(256) void scan_kernel(
    const float* __restrict__ obs, const float* __restrict__ pi,
    const float* __restrict__ P, float* __restrict__ out)
{
    __shared__ float Pl[128 * 128];
    __shared__ float part[2][128];
    __shared__ float e_lds[128];
    __shared__ float redm[2];
    __shared__ float reds[2];
    const float LENLP = -1.791759469228055f;  // -log(6)
    int b = blockIdx.x, tid = threadIdx.x;
    for (int u = tid; u < 4096; u += 256)
        *(float4*)&Pl[u * 4] = *(const float4*)&P[b * 16384 + u * 4];

    float bufr[6];
    if (tid < 128) {
        bufr[0] = pi[b * 128 + tid];
#pragma unroll
        for (int l = 1; l < 6; ++l) bufr[l] = NEGINF_F;
    }
    __syncthreads();

    const int j = tid & 127, half = tid >> 7, k0 = half * 64;

    for (int t = 0; t < 60; ++t) {
        float alpha = NEGINF_F, ev = 0.f;
        if (tid < 128) {
            float vals[6];
            float am = -3.0e38f;
#pragma unroll
            for (int l = 0; l < 6; ++l) {
                int tt = t - l;
                float v = -3.0e38f;
                if (tt >= 0)
                    v = bufr[l] + obs[((l * 60 + tt) * 1024 + b) * 128 + tid] + LENLP;
                vals[l] = v;
                am = fmaxf(am, v);
            }
            float ss = 0.f;
#pragma unroll
            for (int l = 0; l < 6; ++l) ss += expf(vals[l] - am);
            alpha = am + logf(ss);
            float mm = alpha;
#pragma unroll
            for (int off = 32; off >= 1; off >>= 1) mm = fmaxf(mm, __shfl_xor(mm, off, 64));
            if ((tid & 63) == 0) redm[tid >> 6] = mm;
        }
        __syncthreads();
        float m = fmaxf(redm[0], redm[1]);
        if (tid < 128) {
            ev = expf(alpha - m);
            e_lds[tid] = ev;
        }
        __syncthreads();
        float acc = 0.f;
#pragma unroll 8
        for (int kk = 0; kk < 64; ++kk)
            acc = fmaf(e_lds[k0 + kk], Pl[(k0 + kk) * 128 + j], acc);
        part[half][j] = acc;
        __syncthreads();
        if (tid < 128) {
            float s = part[0][tid] + part[1][tid];
            float astar = m + logf(s);
#pragma unroll
            for (int l = 5; l >= 1; --l) bufr[l] = bufr[l - 1];
            bufr[0] = astar;
        }
        if (t == 59) {
            float sv = (tid < 128) ? ev : 0.f;
#pragma unroll
            for (int off = 32; off >= 1; off >>= 1) sv += __shfl_xor(sv, off, 64);
            if (tid < 128 && (tid & 63) == 0) reds[tid >> 6] = sv;
            __syncthreads();
            if (tid == 0) out[b] = m + logf(reds[0] + reds[1]);
        }
    }
}

// ---------------------------------------------------------------------------
extern "C" void kernel_launch(void* const* d_in, const int* in_sizes, int n_in,
                              void* d_out, int out_size, void* d_ws, size_t ws_size,
                              hipStream_t stream)
{
    const float* uniqenc = (const float*)d_in[0];
    const float* obs_lps = (const float*)d_in[1];
    const float* W_init  = (const float*)d_in[2];
    const float* b_init  = (const float*)d_in[3];
    const float* A_from  = (const float*)d_in[4];
    const float* A_to    = (const float*)d_in[5];
    const float* W_c1    = (const float*)d_in[6];
    const float* b_c1    = (const float*)d_in[7];
    const float* W_c2    = (const float*)d_in[8];
    const float* b_c2    = (const float*)d_in[9];
    float* out = (float*)d_out;

    float* ws   = (float*)d_ws;
    float* pi   = ws;                    // 1024*128
    float* cond = pi + 131072;           // 1024*16384
    float* tsc  = cond + 16777216;       // 128*128
    float* P    = tsc + 16384;           // 1024*128*128
    _Float16* u16 = (_Float16*)(P + 16777216);   // 1024*1024 fp16
    _Float16* h16 = u16 + 1048576;               // 1024*8192 fp16

    tsc_kernel<<<128, 128, 0, stream>>>(A_from, A_to, tsc);
    cvt_kernel<<<1024, 256, 0, stream>>>(uniqenc, u16);
    pi_kernel<<<1024, 128, 0, stream>>>(uniqenc, W_init, b_init, pi);
    // GEMM2: h = relu(u @ W_c1 + b_c1)   (1024 x 1024 x 8192), fp16 out
    gemm_f16<1><<<dim3(8, 64), 256, 0, stream>>>(u16, W_c1, b_c1,
                                                 nullptr, h16, 1024, 8192);
    // GEMM3: cond = h @ W_c2 + b_c2      (1024 x 8192 x 16384), fp32 out
    gemm_f16<0><<<dim3(8, 128), 256, 0, stream>>>(h16, W_c2, b_c2,
                                                  cond, nullptr, 8192, 16384);
    trans_kernel<<<1024, 256, 0, stream>>>(cond, tsc, P);
    scan_kernel<<<1024, 256, 0, stream>>>(obs_lps, pi, P, out);
}